// Round 7
// baseline (298.915 us; speedup 1.0000x reference)
//
#include <hip/hip_runtime.h>
#include <hip/hip_fp16.h>

typedef _Float16 f16;
typedef _Float16 f16x8 __attribute__((ext_vector_type(8)));
typedef float f32x4 __attribute__((ext_vector_type(4)));

#define NCH 64         // chunks of 32 rows per batch
#define CHB 32768      // bytes per chunk (32 rows x 256 f32)

// counted waits + barrier in ONE asm: vmcnt(N) for the DMA ring, lgkmcnt(0)
// so pbuf ds_writes are visible across the barrier.
#define WAITB(N) asm volatile("s_waitcnt vmcnt(" #N ") lgkmcnt(0)\n\ts_barrier" ::: "memory")

// ---------------------------------------------------------------------------
// prep_w: W[0][d][k] (k<256, feature half) -> fp16 HI plane, MFMA B-frag order
// [ks(8)][ct(16)][lane(64)][j(8)]: ct=d>>4, lane=(d&15)|(((k>>3)&3)<<4),
// ks=k>>5, j=k&7. Frag (ks,ct) = contiguous 1 KiB.
// ---------------------------------------------------------------------------
__global__ void prep_w(const float* __restrict__ W, f16* __restrict__ wbuf) {
    int idx = blockIdx.x * 256 + threadIdx.x;   // 65536 total
    int d = idx >> 8, k = idx & 255;
    float w = W[d * 512 + k];
    int ct   = d >> 4;
    int lane = (d & 15) | (((k >> 3) & 3) << 4);
    int ks   = k >> 5;
    int j    = k & 7;
    wbuf[(((ks * 16 + ct) * 64) + lane) * 8 + j] = (f16)w;
}

// ---------------------------------------------------------------------------
// prep_c: c[b][d] = sum_e W[0][d][256+e] * h[b][e]   (fp32 exact, tiny)
// ---------------------------------------------------------------------------
__global__ void prep_c(const float* __restrict__ W, const float* __restrict__ h,
                       float* __restrict__ c) {
    __shared__ float hs[256];
    int b = blockIdx.x, d = threadIdx.x;
    hs[d] = h[b * 256 + d];
    __syncthreads();
    const float4* w4 = (const float4*)(W + d * 512 + 256);
    const float4* h4 = (const float4*)hs;
    float acc = 0.f;
#pragma unroll 8
    for (int e = 0; e < 64; ++e) {
        float4 a = w4[e], bb = h4[e];
        acc += a.x * bb.x + a.y * bb.y + a.z * bb.z + a.w * bb.w;
    }
    c[b * 256 + d] = acc;
}

// ---------------------------------------------------------------------------
// main_gemm, 4-waves/SIMD edition:
//   1024 threads = 16 waves = 2 row-halves x 8 col-groups; wave = 16 rows x
//   32 cols -> wf[2][8] (64 VGPR) + acc[2] (8 VGPR): total ~115 regs, so the
//   1024-thread block forces 4 waves/SIMD with NO spill (vs 2 before).
//   A: raw fp32 DMA ring (4 x 32KB slots, depth-3, counted vmcnt; XOR swizzle
//   folded into the global source: L[x] = G[x ^ ((row&7)<<4)], row = x>>10).
//   Scores: per-chunk partials -> 2KB LDS pbuf; a rotating wave reduces the
//   previous chunk's partials right after the barrier (no extra sync, no psc).
// ---------------------------------------------------------------------------
__global__ __launch_bounds__(1024)
void main_gemm(const float* __restrict__ feat, const f16* __restrict__ wbuf,
               const float* __restrict__ cb, const float* __restrict__ vvec,
               float* __restrict__ scores) {
    __shared__ __align__(16) char lds[4 * CHB];    // 128 KiB DMA ring
    __shared__ __align__(16) float pbuf[2][32][8]; // per-chunk partials

    const int tid = threadIdx.x;
    const int w = tid >> 6;       // wave 0..15
    const int l = tid & 63;
    const int g = l >> 4;         // 0..3
    const int lr = l & 15;
    const int rh = w & 1;         // row-half 0/1
    const int cg = w >> 1;        // col-group 0..7 (32 cols each)
    const int b = blockIdx.x;     // batch

    // ---- W-hi fragments for this wave's 32 cols: wf[ct][ks], 64 VGPRs ----
    f16x8 wf[2][8];
    {
        const f16x8* wp = (const f16x8*)wbuf;
#pragma unroll
        for (int ct = 0; ct < 2; ++ct) {
            int ctg = cg * 2 + ct;
#pragma unroll
            for (int ks = 0; ks < 8; ++ks)
                wf[ct][ks] = wp[(ks * 16 + ctg) * 64 + l];
        }
    }
    float c_[2], v_[2];
#pragma unroll
    for (int ct = 0; ct < 2; ++ct) {
        c_[ct] = cb[b * 256 + (cg * 2 + ct) * 16 + lr];
        v_[ct] = vvec[(cg * 2 + ct) * 16 + lr];
    }

    // DMA: 1024 thr x 16 B = 16 KB/round, 2 rounds/chunk. LDS offset
    // x = i*16384 + tid*16 -> row = x>>10 = i*16 + w -> row&7 = w&7.
    const int sj = (tid & ~7) | ((tid ^ w) & 7);
    const char* tbb = (const char*)(feat + (size_t)b * 2048 * 256);

#define ISSUE(u)                                                                   \
    {                                                                              \
        const char* nb = tbb + (size_t)(u) * CHB;                                  \
        char* Q = lds + ((u) & 3) * CHB;                                           \
        _Pragma("unroll")                                                          \
        for (int i = 0; i < 2; ++i)                                                \
            __builtin_amdgcn_global_load_lds(                                      \
                (const __attribute__((address_space(1))) void*)(nb + i * 16384 + sj * 16), \
                (__attribute__((address_space(3))) void*)(Q + i * 16384 + tid * 16),\
                16, 0, 0);                                                         \
    }

    // read addressing (constant per wave): element (row,k) lives at LDS byte
    // (row*1024 + k*4) ^ ((row&7)<<4)
    const int row = rh * 16 + lr;
    const int swz = (row & 7) << 4;
    const int ybase = row * 1024 + g * 32;
    const int o0 = ybase ^ swz;
    const int o1 = (ybase + 16) ^ swz;

    // ---- prologue: chunks 0,1,2 in flight (6 loads/wave) ----
    ISSUE(0); ISSUE(1); ISSUE(2);

    for (int t = 0; t < NCH; ++t) {
        // steady state at loop top (per wave): [t:2][t+1:2][t+2:2](+store) ->
        // wait to 4 retires chunk t exactly; tails peel 2/0.
        if (t < NCH - 2) WAITB(4);
        else if (t == NCH - 2) WAITB(2);
        else WAITB(0);
        if (t + 3 < NCH) ISSUE(t + 3);

        // rotating wave finalizes chunk t-1's scores from pbuf
        if (t > 0 && w == (t & 15) && l < 32) {
            const float* pb = &pbuf[(t - 1) & 1][0][0] + l * 8;
            f32x4 p0 = *(const f32x4*)pb;
            f32x4 p1 = *(const f32x4*)(pb + 4);
            float s = ((p0[0] + p0[1]) + (p0[2] + p0[3])) +
                      ((p1[0] + p1[1]) + (p1[2] + p1[3]));
            scores[(size_t)b * 2048 + (t - 1) * 32 + l] = s;
        }

        const char* P = lds + (t & 3) * CHB;
        f32x4 acc[2] = {};
#pragma unroll
        for (int ks = 0; ks < 8; ++ks) {
            f32x4 r0 = *(const f32x4*)(P + o0 + ks * 128);
            f32x4 r1 = *(const f32x4*)(P + o1 + ks * 128);
            f16x8 ahi, alo;
            ahi[0] = (f16)r0[0]; ahi[1] = (f16)r0[1];
            ahi[2] = (f16)r0[2]; ahi[3] = (f16)r0[3];
            ahi[4] = (f16)r1[0]; ahi[5] = (f16)r1[1];
            ahi[6] = (f16)r1[2]; ahi[7] = (f16)r1[3];
            alo[0] = (f16)(r0[0] - (float)ahi[0]);
            alo[1] = (f16)(r0[1] - (float)ahi[1]);
            alo[2] = (f16)(r0[2] - (float)ahi[2]);
            alo[3] = (f16)(r0[3] - (float)ahi[3]);
            alo[4] = (f16)(r1[0] - (float)ahi[4]);
            alo[5] = (f16)(r1[1] - (float)ahi[5]);
            alo[6] = (f16)(r1[2] - (float)ahi[6]);
            alo[7] = (f16)(r1[3] - (float)ahi[7]);
            acc[0] = __builtin_amdgcn_mfma_f32_16x16x32_f16(ahi, wf[0][ks], acc[0], 0, 0, 0);
            acc[1] = __builtin_amdgcn_mfma_f32_16x16x32_f16(ahi, wf[1][ks], acc[1], 0, 0, 0);
            acc[0] = __builtin_amdgcn_mfma_f32_16x16x32_f16(alo, wf[0][ks], acc[0], 0, 0, 0);
            acc[1] = __builtin_amdgcn_mfma_f32_16x16x32_f16(alo, wf[1][ks], acc[1], 0, 0, 0);
        }

        // ---- epilogue: +c, tanh, *v, reduce over 32 cols -> pbuf partial ----
        // acc[ct][r]: row = rh*16 + g*4 + r, col = (cg*2+ct)*16 + lr
        float s[4];
#pragma unroll
        for (int r = 0; r < 4; ++r) {
            float x0 = acc[0][r] + c_[0];
            float x1 = acc[1][r] + c_[1];
            float t0 = 1.f - __fdividef(2.f, __expf(2.f * x0) + 1.f);
            float t1 = 1.f - __fdividef(2.f, __expf(2.f * x1) + 1.f);
            s[r] = v_[0] * t0 + v_[1] * t1;
        }
#pragma unroll
        for (int m = 1; m < 16; m <<= 1) {
            s[0] += __shfl_xor(s[0], m, 64);
            s[1] += __shfl_xor(s[1], m, 64);
            s[2] += __shfl_xor(s[2], m, 64);
            s[3] += __shfl_xor(s[3], m, 64);
        }
        if (lr == 0) {
            int r0w = rh * 16 + g * 4;
            pbuf[t & 1][r0w + 0][cg] = s[0];
            pbuf[t & 1][r0w + 1][cg] = s[1];
            pbuf[t & 1][r0w + 2][cg] = s[2];
            pbuf[t & 1][r0w + 3][cg] = s[3];
        }
    }
#undef ISSUE

    // ---- flush last chunk's partials ----
    asm volatile("s_waitcnt lgkmcnt(0)\n\ts_barrier" ::: "memory");
    if (w == ((NCH) & 15) && l < 32) {
        const float* pb = &pbuf[(NCH - 1) & 1][0][0] + l * 8;
        f32x4 p0 = *(const f32x4*)pb;
        f32x4 p1 = *(const f32x4*)(pb + 4);
        float s = ((p0[0] + p0[1]) + (p0[2] + p0[3])) +
                  ((p1[0] + p1[1]) + (p1[2] + p1[3]));
        scores[(size_t)b * 2048 + (NCH - 1) * 32 + l] = s;
    }
}

// ---------------------------------------------------------------------------
// softmax over n (2048) per b; out[b*2048+n]
// ---------------------------------------------------------------------------
__global__ void softmax_k(const float* __restrict__ scores, float* __restrict__ out) {
    __shared__ float red[16];
    int b = blockIdx.x, tid = threadIdx.x;  // 256 threads
    const float4* s4 = (const float4*)(scores + (size_t)b * 2048);
    float4 x0 = s4[tid], x1 = s4[tid + 256];
    float m = fmaxf(fmaxf(fmaxf(x0.x, x0.y), fmaxf(x0.z, x0.w)),
                    fmaxf(fmaxf(x1.x, x1.y), fmaxf(x1.z, x1.w)));
#pragma unroll
    for (int d = 1; d < 64; d <<= 1) m = fmaxf(m, __shfl_xor(m, d, 64));
    if ((tid & 63) == 0) red[tid >> 6] = m;
    __syncthreads();
    m = fmaxf(fmaxf(red[0], red[1]), fmaxf(red[2], red[3]));
    float e0 = __expf(x0.x - m), e1 = __expf(x0.y - m), e2 = __expf(x0.z - m), e3 = __expf(x0.w - m);
    float e4 = __expf(x1.x - m), e5 = __expf(x1.y - m), e6 = __expf(x1.z - m), e7 = __expf(x1.w - m);
    float sum = ((e0 + e1) + (e2 + e3)) + ((e4 + e5) + (e6 + e7));
#pragma unroll
    for (int d = 1; d < 64; d <<= 1) sum += __shfl_xor(sum, d, 64);
    if ((tid & 63) == 0) red[8 + (tid >> 6)] = sum;
    __syncthreads();
    sum = (red[8] + red[9]) + (red[10] + red[11]);
    float inv = __fdividef(1.f, sum);
    float4 o0 = {e0 * inv, e1 * inv, e2 * inv, e3 * inv};
    float4 o1 = {e4 * inv, e5 * inv, e6 * inv, e7 * inv};
    float4* o4 = (float4*)(out + (size_t)b * 2048);
    o4[tid] = o0;
    o4[tid + 256] = o1;
}

// ---------------------------------------------------------------------------
extern "C" void kernel_launch(void* const* d_in, const int* in_sizes, int n_in,
                              void* d_out, int out_size, void* d_ws, size_t ws_size,
                              hipStream_t stream) {
    const float* feat = (const float*)d_in[0];   // [256,2048,256]
    const float* h    = (const float*)d_in[1];   // [256,256]
    const float* v    = (const float*)d_in[2];   // [256]
    const float* W    = (const float*)d_in[3];   // [256,512]
    float* out = (float*)d_out;                  // [256,1,2048]

    f16*   wbuf   = (f16*)d_ws;                         // 131072 B (hi plane)
    float* cbuf   = (float*)((char*)d_ws + 131072);     // 262144 B
    float* scores = (float*)((char*)d_ws + 524288);     // 2 MiB

    prep_w<<<256, 256, 0, stream>>>(W, wbuf);
    prep_c<<<256, 256, 0, stream>>>(W, h, cbuf);
    main_gemm<<<256, 1024, 0, stream>>>(feat, wbuf, cbuf, v, scores);
    softmax_k<<<256, 256, 0, stream>>>(scores, out);
}

// Round 9
// 209.497 us; speedup vs baseline: 1.4268x; 1.4268x over previous
//
#include <hip/hip_runtime.h>
#include <hip/hip_fp16.h>

typedef _Float16 f16;
typedef _Float16 f16x4 __attribute__((ext_vector_type(4)));
typedef _Float16 f16x8 __attribute__((ext_vector_type(8)));
typedef __fp16 h16x2 __attribute__((ext_vector_type(2)));
typedef float f32x4 __attribute__((ext_vector_type(4)));

#define NCH 64          // chunks of 32 rows per batch
#define CHB 32768       // bytes per chunk (32 rows x 256 f32)
#define PSTRIDE 524288  // psc plane stride (floats) = 256*2048

#define BAR()    asm volatile("s_waitcnt lgkmcnt(0)\n\ts_barrier" ::: "memory")
#define WAITV(N) asm volatile("s_waitcnt vmcnt(" #N ")" ::: "memory")

// ---------------------------------------------------------------------------
// prep_w: W[0][d][k] (k<256, feature half) -> fp16 HI plane, MFMA B-frag order
// [ks(8)][ct(16)][lane(64)][j(8)]: ct=d>>4, lane=(d&15)|(((k>>3)&3)<<4),
// ks=k>>5, j=k&7. Frag (ks,ct) = contiguous 1 KiB.
// ---------------------------------------------------------------------------
__global__ void prep_w(const float* __restrict__ W, f16* __restrict__ wbuf) {
    int idx = blockIdx.x * 256 + threadIdx.x;   // 65536 total
    int d = idx >> 8, k = idx & 255;
    float w = W[d * 512 + k];
    int ct   = d >> 4;
    int lane = (d & 15) | (((k >> 3) & 3) << 4);
    int ks   = k >> 5;
    int j    = k & 7;
    wbuf[(((ks * 16 + ct) * 64) + lane) * 8 + j] = (f16)w;
}

// ---------------------------------------------------------------------------
// prep_c: c[b][d] = sum_e W[0][d][256+e] * h[b][e]   (fp32 exact, tiny)
// ---------------------------------------------------------------------------
__global__ void prep_c(const float* __restrict__ W, const float* __restrict__ h,
                       float* __restrict__ c) {
    __shared__ float hs[256];
    int b = blockIdx.x, d = threadIdx.x;
    hs[d] = h[b * 256 + d];
    __syncthreads();
    const float4* w4 = (const float4*)(W + d * 512 + 256);
    const float4* h4 = (const float4*)hs;
    float acc = 0.f;
#pragma unroll 8
    for (int e = 0; e < 64; ++e) {
        float4 a = w4[e], bb = h4[e];
        acc += a.x * bb.x + a.y * bb.y + a.z * bb.z + a.w * bb.w;
    }
    c[b * 256 + d] = acc;
}

// ---------------------------------------------------------------------------
// main_gemm: cooperative-cvt pipeline.
//   raw ring: 2 x 32 KB, fp32, LINEAR (DMA src/dst both linear).
//   planes:   2 x 32 KB, f16 hi (16 KB) + f16 lo (16 KB), XOR-swizzled:
//             elem (row,k) at byte (row*512 + k*2) ^ ((row&7)<<4) [granule 16B]
//   Per iter t: BAR -> issue DMA(t+2) -> MFMA planes[t] (pure ds_read+MFMA)
//               -> epilogue compute -> vmcnt(4) -> cvt raw[t+1]->planes[t+1]
//               -> psc store.  cvt runs ONCE per element per CU (pkrtz).
//   8 waves = 2 row-halves x 4 col-groups; wave = 16 rows x 64 cols.
//   wf[4][8]=128 VGPR + acc 16 -> ~190 regs, 2 waves/SIMD, no spill.
// ---------------------------------------------------------------------------
__global__ __launch_bounds__(512, 2)
void main_gemm(const float* __restrict__ feat, const f16* __restrict__ wbuf,
               const float* __restrict__ cb, const float* __restrict__ vvec,
               float* __restrict__ psc) {
    __shared__ __align__(16) char rawb[2 * CHB];    // 64 KiB fp32 ring
    __shared__ __align__(16) char plnb[2 * CHB];    // 64 KiB f16 hi+lo planes

    const int tid = threadIdx.x;
    const int w = tid >> 6;       // wave 0..7
    const int l = tid & 63;
    const int g = l >> 4;         // 0..3
    const int lr = l & 15;
    const int rh = w >> 2;        // row-half 0/1
    const int cg = w & 3;         // col-group 0..3 (64 cols each)
    const int b = blockIdx.x;     // batch

    // ---- W-hi fragments for this wave's 64 cols: wf[ct][ks], 128 VGPRs ----
    f16x8 wf[4][8];
    {
        const f16x8* wp = (const f16x8*)wbuf;
#pragma unroll
        for (int ct = 0; ct < 4; ++ct) {
            int ctg = cg * 4 + ct;
#pragma unroll
            for (int ks = 0; ks < 8; ++ks)
                wf[ct][ks] = wp[(ks * 16 + ctg) * 64 + l];
        }
    }
    float c_[4], v_[4];
#pragma unroll
    for (int ct = 0; ct < 4; ++ct) {
        c_[ct] = cb[b * 256 + (cg * 4 + ct) * 16 + lr];
        v_[ct] = vvec[(cg * 4 + ct) * 16 + lr];
    }

    const char* tbb = (const char*)(feat + (size_t)b * 2048 * 256);

    // DMA: 4 rounds x 512 thr x 16 B = 32 KB, fully linear both sides.
#define ISSUE(u)                                                                   \
    {                                                                              \
        const char* nb = tbb + (size_t)(u) * CHB;                                  \
        char* Q = rawb + ((u) & 1) * CHB;                                          \
        _Pragma("unroll")                                                          \
        for (int i = 0; i < 4; ++i)                                                \
            __builtin_amdgcn_global_load_lds(                                      \
                (const __attribute__((address_space(1))) void*)(nb + i * 8192 + tid * 16), \
                (__attribute__((address_space(3))) void*)(Q + i * 8192 + tid * 16),\
                16, 0, 0);                                                         \
    }

    // cvt-phase addressing: round r handles flat elems r*2048 + tid*4
    //   row = r*8 + w, k0 = (tid&63)*4
    const int ck0 = (tid & 63) * 4;
    int cvt_off[4];
#pragma unroll
    for (int r = 0; r < 4; ++r) {
        int row = r * 8 + w;
        cvt_off[r] = (((row * 512 + (ck0 & ~7) * 2) ^ ((row & 7) << 4)) +
                      ((ck0 & 4) << 1));
    }

#define CVT(u)                                                                     \
    {                                                                              \
        const char* rp = rawb + ((u) & 1) * CHB;                                   \
        char* hp = plnb + ((u) & 1) * CHB;                                         \
        _Pragma("unroll")                                                          \
        for (int r = 0; r < 4; ++r) {                                              \
            f32x4 x = *(const f32x4*)(rp + r * 8192 + tid * 16);                   \
            h16x2 h01 = __builtin_amdgcn_cvt_pkrtz(x[0], x[1]);                    \
            h16x2 h23 = __builtin_amdgcn_cvt_pkrtz(x[2], x[3]);                    \
            h16x2 l01 = __builtin_amdgcn_cvt_pkrtz(x[0] - (float)h01[0],           \
                                                   x[1] - (float)h01[1]);          \
            h16x2 l23 = __builtin_amdgcn_cvt_pkrtz(x[2] - (float)h23[0],           \
                                                   x[3] - (float)h23[1]);          \
            f16x4 hv = {(f16)(float)h01[0], (f16)(float)h01[1],                    \
                        (f16)(float)h23[0], (f16)(float)h23[1]};                   \
            f16x4 lv = {(f16)(float)l01[0], (f16)(float)l01[1],                    \
                        (f16)(float)l23[0], (f16)(float)l23[1]};                   \
            *(f16x4*)(hp + cvt_off[r]) = hv;                                       \
            *(f16x4*)(hp + 16384 + cvt_off[r]) = lv;                               \
        }                                                                          \
    }

    // MFMA-phase A addressing (constant per lane): row = rh*16+lr
    const int arow = rh * 16 + lr;
    const int aswz = (arow & 7) << 4;

    // ---- prologue: DMA chunks 0,1; cvt chunk 0 ----
    ISSUE(0); ISSUE(1);
    WAITV(4);            // raw[0] complete (raw[1] still flying)
    CVT(0);

    for (int t = 0; t < NCH; ++t) {
        BAR();           // planes[t] visible; raw slot (t&1) free for DMA
        if (t + 2 < NCH) ISSUE(t + 2);

        const char* hp = plnb + (t & 1) * CHB;
        f32x4 acc[4] = {};
#pragma unroll
        for (int ks = 0; ks < 8; ++ks) {
            int ao = (arow * 512 + ks * 64 + g * 16) ^ aswz;
            f16x8 ahi = *(const f16x8*)(hp + ao);
            f16x8 alo = *(const f16x8*)(hp + 16384 + ao);
            acc[0] = __builtin_amdgcn_mfma_f32_16x16x32_f16(ahi, wf[0][ks], acc[0], 0, 0, 0);
            acc[1] = __builtin_amdgcn_mfma_f32_16x16x32_f16(ahi, wf[1][ks], acc[1], 0, 0, 0);
            acc[2] = __builtin_amdgcn_mfma_f32_16x16x32_f16(ahi, wf[2][ks], acc[2], 0, 0, 0);
            acc[3] = __builtin_amdgcn_mfma_f32_16x16x32_f16(ahi, wf[3][ks], acc[3], 0, 0, 0);
            acc[0] = __builtin_amdgcn_mfma_f32_16x16x32_f16(alo, wf[0][ks], acc[0], 0, 0, 0);
            acc[1] = __builtin_amdgcn_mfma_f32_16x16x32_f16(alo, wf[1][ks], acc[1], 0, 0, 0);
            acc[2] = __builtin_amdgcn_mfma_f32_16x16x32_f16(alo, wf[2][ks], acc[2], 0, 0, 0);
            acc[3] = __builtin_amdgcn_mfma_f32_16x16x32_f16(alo, wf[3][ks], acc[3], 0, 0, 0);
        }

        // ---- epilogue compute: +c, tanh, *v, reduce over 64 cols ----
        // acc[ct][r]: row = rh*16 + g*4 + r, col = (cg*4+ct)*16 + lr
        float s[4];
#pragma unroll
        for (int r = 0; r < 4; ++r) {
            float a = 0.f;
#pragma unroll
            for (int ct = 0; ct < 4; ++ct) {
                float x = acc[ct][r] + c_[ct];
                float tnh = 1.f - __fdividef(2.f, __expf(2.f * x) + 1.f);
                a += v_[ct] * tnh;
            }
            s[r] = a;
        }
#pragma unroll
        for (int m = 1; m < 16; m <<= 1) {
            s[0] += __shfl_xor(s[0], m, 64);
            s[1] += __shfl_xor(s[1], m, 64);
            s[2] += __shfl_xor(s[2], m, 64);
            s[3] += __shfl_xor(s[3], m, 64);
        }

        // ---- retire raw[t+1], cvt it (raw[t+2] stays in flight) ----
        if (t < NCH - 2)      WAITV(4);
        else if (t == NCH - 2) WAITV(0);
        if (t + 1 < NCH) CVT(t + 1);

        if (lr == 0) {
            size_t rowg = (size_t)b * 2048 + t * 32 + rh * 16 + g * 4;
            float4 o = {s[0], s[1], s[2], s[3]};
            *(float4*)(psc + (size_t)cg * PSTRIDE + rowg) = o;
        }
    }
#undef ISSUE
#undef CVT
}

// ---------------------------------------------------------------------------
// softmax over n (2048) per b, summing 4 plane partials per row.
// ---------------------------------------------------------------------------
__global__ void softmax_k(const float* __restrict__ psc, float* __restrict__ out) {
    __shared__ float red[16];
    int b = blockIdx.x, tid = threadIdx.x;  // 256 threads
    float sc[8];
    float m = -3.4e38f;
#pragma unroll
    for (int q = 0; q < 8; ++q) {
        size_t row = (size_t)b * 2048 + q * 256 + tid;
        sc[q] = (psc[row] + psc[PSTRIDE + row]) +
                (psc[2 * PSTRIDE + row] + psc[3 * PSTRIDE + row]);
        m = fmaxf(m, sc[q]);
    }
#pragma unroll
    for (int d = 1; d < 64; d <<= 1) m = fmaxf(m, __shfl_xor(m, d, 64));
    if ((tid & 63) == 0) red[tid >> 6] = m;
    __syncthreads();
    m = fmaxf(fmaxf(red[0], red[1]), fmaxf(red[2], red[3]));
    float e[8], sum = 0.f;
#pragma unroll
    for (int q = 0; q < 8; ++q) { e[q] = __expf(sc[q] - m); sum += e[q]; }
#pragma unroll
    for (int d = 1; d < 64; d <<= 1) sum += __shfl_xor(sum, d, 64);
    if ((tid & 63) == 0) red[8 + (tid >> 6)] = sum;
    __syncthreads();
    sum = (red[8] + red[9]) + (red[10] + red[11]);
    float inv = __fdividef(1.f, sum);
#pragma unroll
    for (int q = 0; q < 8; ++q)
        out[(size_t)b * 2048 + q * 256 + tid] = e[q] * inv;
}

// ---------------------------------------------------------------------------
extern "C" void kernel_launch(void* const* d_in, const int* in_sizes, int n_in,
                              void* d_out, int out_size, void* d_ws, size_t ws_size,
                              hipStream_t stream) {
    const float* feat = (const float*)d_in[0];   // [256,2048,256]
    const float* h    = (const float*)d_in[1];   // [256,256]
    const float* v    = (const float*)d_in[2];   // [256]
    const float* W    = (const float*)d_in[3];   // [256,512]
    float* out = (float*)d_out;                  // [256,1,2048]

    f16*   wbuf = (f16*)d_ws;                         // 131072 B (hi plane)
    float* cbuf = (float*)((char*)d_ws + 131072);     // 262144 B
    float* psc  = (float*)((char*)d_ws + 524288);     // 4 planes x 2 MiB

    prep_w<<<256, 256, 0, stream>>>(W, wbuf);
    prep_c<<<256, 256, 0, stream>>>(W, h, cbuf);
    main_gemm<<<256, 512, 0, stream>>>(feat, wbuf, cbuf, v, psc);
    softmax_k<<<256, 256, 0, stream>>>(psc, out);
}